// Round 10
// baseline (318.784 us; speedup 1.0000x reference)
//
#include <hip/hip_runtime.h>

#define THREADS 256
#define B1 256          // partition blocks for P1/P2 (edge chunks)

typedef __attribute__((ext_vector_type(8))) short bf16x8;   // 8 bf16 (4 VGPR)
typedef __attribute__((ext_vector_type(4))) float f32x4;
typedef __attribute__((ext_vector_type(2))) unsigned int u32x2;

// ---- bf16 helpers ----
__device__ inline ushort f2bf(float v) {
    union { float f; unsigned u; } a; a.f = v;
    unsigned r = a.u + 0x7fff + ((a.u >> 16) & 1);
    return (ushort)(r >> 16);
}
__device__ inline unsigned pack2(float a, float b) {
    return (unsigned)f2bf(a) | ((unsigned)f2bf(b) << 16);
}

// =================== CSR build (round-4 proven version) =====================

__global__ void k_p1(const int* __restrict__ dst, int* __restrict__ pc,
                     int E, int NB, int chunk) {
    __shared__ int hist[512];
    int tid = threadIdx.x, blk = blockIdx.x;
    for (int i = tid; i < NB; i += THREADS) hist[i] = 0;
    __syncthreads();
    int e0 = blk * chunk;
    int e1 = e0 + chunk; if (e1 > E) e1 = E;
    for (int e = e0 + tid; e < e1; e += THREADS)
        atomicAdd(&hist[dst[e] >> 8], 1);
    __syncthreads();
    for (int i = tid; i < NB; i += THREADS) pc[i * B1 + blk] = hist[i];
}

__global__ void k_s1(int* __restrict__ pc, int* __restrict__ bsums, int total) {
    __shared__ int s[1024];
    int t = threadIdx.x;
    int idx = blockIdx.x * 1024 + t;
    int v = (idx < total) ? pc[idx] : 0;
    s[t] = v;
    __syncthreads();
    for (int o = 1; o < 1024; o <<= 1) {
        int x = (t >= (unsigned)o) ? s[t - o] : 0;
        __syncthreads();
        s[t] += x;
        __syncthreads();
    }
    if (idx < total) pc[idx] = s[t] - v;           // exclusive within block
    if (t == 1023) bsums[blockIdx.x] = s[1023];    // block total
}

__global__ void k_s2(int* __restrict__ bsums, int nb) {
    __shared__ int s[128];
    int t = threadIdx.x;
    int v = (t < nb) ? bsums[t] : 0;
    s[t] = v;
    __syncthreads();
    for (int o = 1; o < 128; o <<= 1) {
        int x = (t >= (unsigned)o) ? s[t - o] : 0;
        __syncthreads();
        s[t] += x;
        __syncthreads();
    }
    if (t < nb) bsums[t] = s[t] - v;
}

__global__ void k_p2(const int* __restrict__ src, const int* __restrict__ dst,
                     const int* __restrict__ pc, const int* __restrict__ bsx,
                     unsigned long long* __restrict__ part, int E, int NB, int chunk) {
    __shared__ int cur[512];
    int tid = threadIdx.x, blk = blockIdx.x;
    for (int i = tid; i < NB; i += THREADS) {
        int idx = i * B1 + blk;
        cur[i] = pc[idx] + bsx[idx >> 10];
    }
    __syncthreads();
    int e0 = blk * chunk;
    int e1 = e0 + chunk; if (e1 > E) e1 = E;
    for (int e = e0 + tid; e < e1; e += THREADS) {
        int d = dst[e], sv = src[e];
        int pos = atomicAdd(&cur[d >> 8], 1);      // LDS atomic
        part[pos] = ((unsigned long long)(unsigned)d << 32) | (unsigned)sv;
    }
}

// k_p3 also zeroes cnt[] (node-mapped), replacing a host-side memset.
__global__ void k_p3(const unsigned long long* __restrict__ part,
                     const int* __restrict__ pc, const int* __restrict__ bsx,
                     int* __restrict__ off, float* __restrict__ dinv,
                     int* __restrict__ csr, float* __restrict__ cnt,
                     int E, int NB, int n) {
    __shared__ int hist[256];
    __shared__ int so[256];
    int b = blockIdx.x, t = threadIdx.x;
    int i0 = b * B1, i1 = (b + 1) * B1;
    int base = pc[i0] + bsx[i0 >> 10];
    int end  = (b + 1 < NB) ? (pc[i1] + bsx[i1 >> 10]) : E;
    hist[t] = 0;
    __syncthreads();
    for (int e = base + t; e < end; e += THREADS)
        atomicAdd(&hist[(int)(part[e] >> 32) & 255], 1);
    __syncthreads();
    int h = hist[t];
    so[t] = h;
    __syncthreads();
    for (int o = 1; o < 256; o <<= 1) {
        int x = (t >= (unsigned)o) ? so[t - o] : 0;
        __syncthreads();
        so[t] += x;
        __syncthreads();
    }
    int ex = so[t] - h;                            // exclusive within bucket
    int node = (b << 8) + t;
    if (node < n) {
        off[node]  = base + ex;
        dinv[node] = rsqrtf((float)h + 1.0f);
        cnt[node]  = 0.0f;                         // fused memset
        if (node == n - 1) off[n] = E;
    }
    __syncthreads();
    so[t] = base + ex;                             // cursors
    __syncthreads();
    for (int e = base + t; e < end; e += THREADS) {
        unsigned long long p = part[e];
        int pos = atomicAdd(&so[(int)(p >> 32) & 255], 1);   // LDS atomic
        csr[pos] = (int)(p & 0xffffffffu);
    }
}

// =================== MFMA dense GEMM: C = (X @ W) * dinv -> bf16 ===========
template<int KTILES, bool XF32>
__global__ __launch_bounds__(THREADS) void
k_mgemm(const float* __restrict__ Xf, const ushort* __restrict__ Xh,
        const float* __restrict__ W, const float* __restrict__ dinv,
        ushort* __restrict__ C, int n,
        const int* __restrict__ dict, float* __restrict__ cnt,
        float* __restrict__ pool16, int nGemm, int nCnt, int nZero) {
    int tid = threadIdx.x;
    if ((int)blockIdx.x >= nGemm) {
        int rb = (int)blockIdx.x - nGemm;
        if (rb < nCnt) {
            // ---- cnt role: dict histogram (hidden under the GEMM) ----
            int stride = nCnt * THREADS;
            for (int i = rb * THREADS + tid; i < n; i += stride)
                atomicAdd(&cnt[dict[i]], 1.0f);
        } else {
            // ---- zero role: pool16 = 0 (replaces host memset) ----
            int zb = rb - nCnt;
            uint4* p4 = (uint4*)pool16;
            int tot = n * 4;                 // n*16 floats = n*4 uint4
            int stride = nZero * THREADS;
            uint4 z = {0, 0, 0, 0};
            for (int i = zb * THREADS + tid; i < tot; i += stride) p4[i] = z;
        }
        return;
    }
    __shared__ ushort wfrag[KTILES * 2048];   // KTILES*4 tiles * 64 lanes * 8 bf16
    __shared__ float hrow[4][16 * 64];        // per-wave repack buffer (16 KB)
    const int FIN = KTILES * 32;
    for (int i = tid; i < FIN * 64; i += THREADS) {
        int k = i >> 6, c = i & 63;           // W[k][c], row-major [FIN][64]
        int kk = k >> 5, G = (k >> 3) & 3, e = k & 7;
        int t = c >> 4, c16 = c & 15;
        wfrag[(((kk * 4 + t) * 64) + G * 16 + c16) * 8 + e] = f2bf(W[i]);
    }
    __syncthreads();
    int wslot = tid >> 6, lane = tid & 63;
    int G = lane >> 4, c16 = lane & 15;
    int n0 = blockIdx.x * 64 + wslot * 16;
    int xrow = n0 + c16; if (xrow >= n) xrow = n - 1;
    const bf16x8* wf = (const bf16x8*)wfrag;
    f32x4 acc0 = {0, 0, 0, 0}, acc1 = acc0, acc2 = acc0, acc3 = acc0;
    #pragma unroll
    for (int kk = 0; kk < KTILES; ++kk) {
        bf16x8 a;
        if (XF32) {
            const float* xp = Xf + (size_t)xrow * FIN + kk * 32 + G * 8;
            float4 xa = *(const float4*)xp;
            float4 xb = *(const float4*)(xp + 4);
            a[0] = (short)f2bf(xa.x); a[1] = (short)f2bf(xa.y);
            a[2] = (short)f2bf(xa.z); a[3] = (short)f2bf(xa.w);
            a[4] = (short)f2bf(xb.x); a[5] = (short)f2bf(xb.y);
            a[6] = (short)f2bf(xb.z); a[7] = (short)f2bf(xb.w);
        } else {
            a = *(const bf16x8*)(Xh + (size_t)xrow * FIN + kk * 32 + G * 8);
        }
        bf16x8 b0 = wf[(kk * 4 + 0) * 64 + lane];
        bf16x8 b1 = wf[(kk * 4 + 1) * 64 + lane];
        bf16x8 b2 = wf[(kk * 4 + 2) * 64 + lane];
        bf16x8 b3 = wf[(kk * 4 + 3) * 64 + lane];
        acc0 = __builtin_amdgcn_mfma_f32_16x16x32_bf16(a, b0, acc0, 0, 0, 0);
        acc1 = __builtin_amdgcn_mfma_f32_16x16x32_bf16(a, b1, acc1, 0, 0, 0);
        acc2 = __builtin_amdgcn_mfma_f32_16x16x32_bf16(a, b2, acc2, 0, 0, 0);
        acc3 = __builtin_amdgcn_mfma_f32_16x16x32_bf16(a, b3, acc3, 0, 0, 0);
    }
    // ---- epilogue: D row=G*4+r, col=c16+16t; dinv scale; LDS repack ----
    int vm = n - n0; if (vm > 16) vm = 16;    // may be <=0 for tail waves
    float* hr = &hrow[wslot][0];
    #pragma unroll
    for (int r = 0; r < 4; ++r) {
        int rr = G * 4 + r;
        if (rr < vm) {
            float dn = dinv[n0 + rr];
            hr[rr * 64 + c16]      = acc0[r] * dn;
            hr[rr * 64 + c16 + 16] = acc1[r] * dn;
            hr[rr * 64 + c16 + 32] = acc2[r] * dn;
            hr[rr * 64 + c16 + 48] = acc3[r] * dn;
        }
    }
    asm volatile("" ::: "memory");            // same-wave LDS RAW ordering
    int prow = lane >> 2, pseg = lane & 3;    // 16 rows x 4 col-segments
    if (prow < vm) {
        const float* hp = hr + prow * 64 + pseg * 16;
        float4 f0 = *(const float4*)(hp + 0);
        float4 f1 = *(const float4*)(hp + 4);
        float4 f2 = *(const float4*)(hp + 8);
        float4 f3 = *(const float4*)(hp + 12);
        uint4 o0, o1;
        o0.x = pack2(f0.x, f0.y); o0.y = pack2(f0.z, f0.w);
        o0.z = pack2(f1.x, f1.y); o0.w = pack2(f1.z, f1.w);
        o1.x = pack2(f2.x, f2.y); o1.y = pack2(f2.z, f2.w);
        o1.z = pack2(f3.x, f3.y); o1.w = pack2(f3.z, f3.w);
        ushort* op = C + ((size_t)(n0 + prow) << 6) + pseg * 16;
        *(uint4*)(op)     = o0;
        *(uint4*)(op + 8) = o1;
    }
}

// =================== MFMA aggregation (unrolled x3, static buffers) =========
__device__ inline void tr_mfma4(unsigned la, const bf16x8& a,
                                f32x4& o0, f32x4& o1, f32x4& o2, f32x4& o3) {
    u32x2 r0, r1, r2, r3, r4, r5, r6, r7;
    asm volatile(
        "s_waitcnt lgkmcnt(0)\n\t"
        "ds_read_b64_tr_b16 %0, %8 offset:0\n\t"
        "ds_read_b64_tr_b16 %1, %8 offset:512\n\t"
        "ds_read_b64_tr_b16 %2, %8 offset:1024\n\t"
        "ds_read_b64_tr_b16 %3, %8 offset:1536\n\t"
        "ds_read_b64_tr_b16 %4, %8 offset:2048\n\t"
        "ds_read_b64_tr_b16 %5, %8 offset:2560\n\t"
        "ds_read_b64_tr_b16 %6, %8 offset:3072\n\t"
        "ds_read_b64_tr_b16 %7, %8 offset:3584\n\t"
        "s_waitcnt lgkmcnt(0)"
        : "=&v"(r0), "=&v"(r1), "=&v"(r2), "=&v"(r3),
          "=&v"(r4), "=&v"(r5), "=&v"(r6), "=&v"(r7)
        : "v"(la) : "memory");
    __builtin_amdgcn_sched_barrier(0);       // keep MFMAs after the waitcnt
    union { u32x2 d[2]; bf16x8 v; } b0, b1, b2, b3;
    b0.d[0] = r0; b0.d[1] = r1; b1.d[0] = r2; b1.d[1] = r3;
    b2.d[0] = r4; b2.d[1] = r5; b3.d[0] = r6; b3.d[1] = r7;
    o0 = __builtin_amdgcn_mfma_f32_16x16x32_bf16(a, b0.v, o0, 0, 0, 0);
    o1 = __builtin_amdgcn_mfma_f32_16x16x32_bf16(a, b1.v, o1, 0, 0, 0);
    o2 = __builtin_amdgcn_mfma_f32_16x16x32_bf16(a, b2.v, o2, 0, 0, 0);
    o3 = __builtin_amdgcn_mfma_f32_16x16x32_bf16(a, b3.v, o3, 0, 0, 0);
}

// load chunk at edge-base bb into buf (guarded; OOB lanes get 0)
#define AGG_LOAD(buf, bb)                                                   \
    {                                                                       \
        _Pragma("unroll")                                                   \
        for (int it = 0; it < 4; ++it) {                                    \
            uint4 v = {0, 0, 0, 0};                                         \
            int k = (bb) + it * 8 + g8;                                     \
            if (k < baseEnd) {                                              \
                int e = csr[k];                                             \
                v = *(const uint4*)(H + ((size_t)e << 6) + q * 8);          \
            }                                                               \
            buf[it] = v;                                                    \
        }                                                                   \
    }

// stage buf to LDS, build indicator for edge-base bb, do 4 MFMAs
#define AGG_STEP(buf, bb)                                                   \
    {                                                                       \
        _Pragma("unroll")                                                   \
        for (int it = 0; it < 4; ++it)                                      \
            *(uint4*)(wbuf + sb0 + it * 64) = buf[it];                      \
        int kb = (bb) - sA;                                                 \
        bf16x8 a;                                                           \
        _Pragma("unroll")                                                   \
        for (int e2 = 0; e2 < 8; ++e2)                                      \
            a[e2] = ((unsigned)(G * 8 + e2 + kb) < rng) ? (short)0x3F80     \
                                                        : (short)0;         \
        tr_mfma4(la, a, acc0, acc1, acc2, acc3);                            \
    }

// LAYER 1: relu(acc*dinv + b1) -> bf16 rows (coalesced via LDS repack)
// LAYER 2: relu(acc*dinv + b2) -> FC(64->16) -> atomicAdd pool16[dict[node]]
// No block barriers; no wt in LDS (Wfc read from global, L1-resident 4KB).
template<int LAYER>
__global__ __launch_bounds__(THREADS) void
k_agg(const ushort* __restrict__ H, const int* __restrict__ csr,
      const int* __restrict__ off, const float* __restrict__ dinv,
      const float* __restrict__ bias, ushort* __restrict__ outB,
      const float* __restrict__ Wfc, const int* __restrict__ dict,
      float* __restrict__ pool16, int n) {
    __shared__ ushort cbuf[4][2048];          // 4KB per wave, per-wave private
    int tid = threadIdx.x;
    int wslot = tid >> 6, lane = tid & 63;
    int gw = blockIdx.x * 4 + wslot;
    int n0 = gw << 4;
    if (n0 >= n) return;
    int G = lane >> 4, c16 = lane & 15;
    int g8 = lane >> 3, q = lane & 7;
    ushort* wbuf = &cbuf[wslot][0];
    unsigned lbase = (unsigned)(size_t)wbuf;  // LDS byte offset
    int vm = n - n0; if (vm > 16) vm = 16;
    int sA = 0, eA = 0;
    if (c16 < vm) { sA = off[n0 + c16]; eA = off[n0 + c16 + 1]; }
    int base0   = __shfl(sA, 0);
    int baseEnd = __shfl(eA, vm - 1);
    unsigned rng = (unsigned)(eA - sA);
    int sb0 = (q >> 1) * 512 + (g8 >> 2) * 256 + (g8 & 3) * 16 + (q & 1) * 8;
    unsigned la = lbase + (unsigned)lane * 8; // tr-read base (bytes)
    f32x4 acc0 = {0, 0, 0, 0}, acc1 = acc0, acc2 = acc0, acc3 = acc0;

    // 3-deep pipeline, unrolled x3: no register rotation, no early waits.
    uint4 b0[4], b1[4], b2[4];
    int base = base0;
    AGG_LOAD(b0, base);
    AGG_LOAD(b1, base + 32);
    while (base < baseEnd) {
        AGG_LOAD(b2, base + 64);
        AGG_STEP(b0, base);
        base += 32;
        if (base >= baseEnd) break;
        AGG_LOAD(b0, base + 64);
        AGG_STEP(b1, base);
        base += 32;
        if (base >= baseEnd) break;
        AGG_LOAD(b1, base + 64);
        AGG_STEP(b2, base);
        base += 32;
    }
    {   // self-loop chunk: rows 0..15 = H[n0..n0+15], A = identity
        #pragma unroll
        for (int it = 0; it < 4; ++it) {
            uint4 v = {0, 0, 0, 0};
            int k = it * 8 + g8;
            if (it < 2 && k < vm)
                v = *(const uint4*)(H + ((size_t)(n0 + k) << 6) + q * 8);
            *(uint4*)(wbuf + sb0 + it * 64) = v;
        }
        bf16x8 a;
        #pragma unroll
        for (int e2 = 0; e2 < 8; ++e2)
            a[e2] = ((G * 8 + e2) == c16) ? (short)0x3F80 : (short)0;
        tr_mfma4(la, a, acc0, acc1, acc2, acc3);
    }
    // ---- epilogue: D layout col=lane&15 (=c16), row=G*4+r ----
    float* hrow = (float*)wbuf;               // 16x64 f32, aliases staging buf
    float bv0 = bias[c16], bv1 = bias[c16 + 16],
          bv2 = bias[c16 + 32], bv3 = bias[c16 + 48];
    #pragma unroll
    for (int r = 0; r < 4; ++r) {
        int rr = G * 4 + r;
        if (rr < vm) {
            float dn = dinv[n0 + rr];
            float v0 = fmaxf(acc0[r] * dn + bv0, 0.f);
            float v1 = fmaxf(acc1[r] * dn + bv1, 0.f);
            float v2 = fmaxf(acc2[r] * dn + bv2, 0.f);
            float v3 = fmaxf(acc3[r] * dn + bv3, 0.f);
            hrow[rr * 64 + c16]      = v0;
            hrow[rr * 64 + c16 + 16] = v1;
            hrow[rr * 64 + c16 + 32] = v2;
            hrow[rr * 64 + c16 + 48] = v3;
        }
    }
    asm volatile("" ::: "memory");            // order hrow writes vs reads
    if (LAYER == 1) {
        int prow = lane >> 2, pseg = lane & 3;   // 16 rows x 4 col-segments
        if (prow < vm) {
            const float* hp = hrow + prow * 64 + pseg * 16;
            float4 f0 = *(const float4*)(hp + 0);
            float4 f1 = *(const float4*)(hp + 4);
            float4 f2 = *(const float4*)(hp + 8);
            float4 f3 = *(const float4*)(hp + 12);
            uint4 o0, o1;
            o0.x = pack2(f0.x, f0.y); o0.y = pack2(f0.z, f0.w);
            o0.z = pack2(f1.x, f1.y); o0.w = pack2(f1.z, f1.w);
            o1.x = pack2(f2.x, f2.y); o1.y = pack2(f2.z, f2.w);
            o1.z = pack2(f3.x, f3.y); o1.w = pack2(f3.z, f3.w);
            ushort* op = outB + ((size_t)(n0 + prow) << 6) + pseg * 16;
            *(uint4*)(op)     = o0;
            *(uint4*)(op + 8) = o1;
        }
    } else {
        // FC: lane (G, c16): class r16=c16, col quarter G; Wfc from global
        float wr[16];
        #pragma unroll
        for (int i = 0; i < 16; ++i)
            wr[i] = Wfc[(G * 16 + i) * 16 + c16];   // Wfc[cc*16 + r]
        for (int m = 0; m < vm; ++m) {
            const float* hm = hrow + m * 64 + G * 16;
            float p = 0.f;
            #pragma unroll
            for (int i = 0; i < 16; ++i) p = fmaf(hm[i], wr[i], p);
            p += __shfl_xor(p, 16);
            p += __shfl_xor(p, 32);
            if (G == 0)
                atomicAdd(&pool16[(size_t)dict[n0 + m] * 16 + c16], p);
        }
    }
}

// ---------- mean + bias + log_softmax over 16 classes ----------
__global__ void k_final16(const float* __restrict__ pool16, const float* __restrict__ cnt,
                          const float* __restrict__ bfc, float* __restrict__ out, int n) {
    int tid = threadIdx.x;
    int nl = tid >> 4, lane = tid & 15;
    int node = blockIdx.x * 16 + nl;
    if (node >= n) return;
    float inv = 1.0f / fmaxf(cnt[node], 1.0f);
    float acc = pool16[(size_t)node * 16 + lane] * inv + bfc[lane];
    float m = acc;
    for (int o = 8; o; o >>= 1) m = fmaxf(m, __shfl_xor(m, o, 16));
    float ex = __expf(acc - m);
    float s = ex;
    for (int o = 8; o; o >>= 1) s += __shfl_xor(s, o, 16);
    out[(size_t)node * 16 + lane] = acc - m - __logf(s);
}

extern "C" void kernel_launch(void* const* d_in, const int* in_sizes, int n_in,
                              void* d_out, int out_size, void* d_ws, size_t ws_size,
                              hipStream_t stream) {
    const float* x    = (const float*)d_in[0];
    const int*   ei   = (const int*)d_in[1];
    const int*   dict = (const int*)d_in[2];
    const float* W1   = (const float*)d_in[3];
    const float* b1   = (const float*)d_in[4];
    const float* W2   = (const float*)d_in[5];
    const float* b2   = (const float*)d_in[6];
    const float* Wfc  = (const float*)d_in[7];
    const float* bfc  = (const float*)d_in[8];

    const int N  = in_sizes[2];          // 100000
    const int E  = in_sizes[1] / 2;      // 1600000
    const int IN = in_sizes[0] / N;      // 128
    const int* src = ei;
    const int* dst = ei + E;

    // workspace layout (~40 MB, round-4 proven plan)
    ushort* bufA = (ushort*)d_ws;                        // N*64 bf16
    ushort* bufB = bufA + (size_t)N * 64;                // N*64 bf16
    unsigned long long* part = (unsigned long long*)bufB;  // E u64 (alias bufB)
    float* dinv    = (float*)(bufB + (size_t)N * 64);    // N
    float* cnt     = dinv + N;                           // N
    int*   off     = (int*)(cnt + N);                    // N+1
    int*   pcounts = off + (N + 1);                      // NB*B1
    const int NB     = (N + 255) >> 8;                   // 391
    const int pcsize = NB * B1;                          // 100096
    int*   bsums   = pcounts + pcsize;                   // 128
    int*   csr     = bsums + 128;                        // E
    float* pool16  = (float*)(csr + E);                  // N*16

    const int gTile = (N + 63) / 64;                     // 1563
    const int gRows = (N + 15) / 16;                     // 6250
    const int nCnt  = 256;
    const int nZero = 256;
    const int chunk = (E + B1 - 1) / B1;                 // 6250
    const int nS1   = (pcsize + 1023) >> 10;             // 98
    const int gAgg  = ((N + 15) / 16 + 3) / 4;           // 1563 (4 waves/block)

    // CSR build: LDS counting sort (no global atomics); p3 also zeroes cnt
    k_p1<<<B1, THREADS, 0, stream>>>(dst, pcounts, E, NB, chunk);
    k_s1<<<nS1, 1024, 0, stream>>>(pcounts, bsums, pcsize);
    k_s2<<<1, 128, 0, stream>>>(bsums, nS1);
    k_p2<<<B1, THREADS, 0, stream>>>(src, dst, pcounts, bsums, part, E, NB, chunk);
    k_p3<<<NB, THREADS, 0, stream>>>(part, pcounts, bsums, off, dinv, csr, cnt,
                                     E, NB, N);

    // GEMM1 (MFMA): bufA = bf16((x@W1)*dinv)  (+ cnt histogram + pool16 zero)
    k_mgemm<4, true><<<gTile + nCnt + nZero, THREADS, 0, stream>>>(
        x, nullptr, W1, dinv, bufA, N, dict, cnt, pool16, gTile, nCnt, nZero);

    // layer 1 MFMA aggregation: bufB = bf16(relu(dn*(sum+self)+b1))
    k_agg<1><<<gAgg, THREADS, 0, stream>>>(bufA, csr, off, dinv, b1, bufB,
                                           nullptr, nullptr, nullptr, N);

    // GEMM2 (MFMA): bufA = bf16((bufB@W2)*dinv); then agg2
    k_mgemm<2, false><<<gTile, THREADS, 0, stream>>>(
        nullptr, bufB, W2, dinv, bufA, N, nullptr, nullptr, nullptr, gTile, 0, 0);
    k_agg<2><<<gAgg, THREADS, 0, stream>>>(bufA, csr, off, dinv, b2, nullptr,
                                           Wfc, dict, pool16, N);

    // mean + bias + log_softmax
    k_final16<<<gRows, THREADS, 0, stream>>>(pool16, cnt, bfc, (float*)d_out, N);
}

// Round 11
// 281.321 us; speedup vs baseline: 1.1332x; 1.1332x over previous
//
#include <hip/hip_runtime.h>

#define THREADS 256
#define B1 256          // partition blocks for P1/P2 (edge chunks)

typedef __attribute__((ext_vector_type(8))) short bf16x8;   // 8 bf16 (4 VGPR)
typedef __attribute__((ext_vector_type(4))) float f32x4;
typedef __attribute__((ext_vector_type(2))) unsigned int u32x2;

// ---- bf16 helpers ----
__device__ inline ushort f2bf(float v) {
    union { float f; unsigned u; } a; a.f = v;
    unsigned r = a.u + 0x7fff + ((a.u >> 16) & 1);
    return (ushort)(r >> 16);
}
__device__ inline unsigned pack2(float a, float b) {
    return (unsigned)f2bf(a) | ((unsigned)f2bf(b) << 16);
}

// =================== CSR build (round-4 proven version) =====================

__global__ void k_p1(const int* __restrict__ dst, int* __restrict__ pc,
                     int E, int NB, int chunk) {
    __shared__ int hist[512];
    int tid = threadIdx.x, blk = blockIdx.x;
    for (int i = tid; i < NB; i += THREADS) hist[i] = 0;
    __syncthreads();
    int e0 = blk * chunk;
    int e1 = e0 + chunk; if (e1 > E) e1 = E;
    for (int e = e0 + tid; e < e1; e += THREADS)
        atomicAdd(&hist[dst[e] >> 8], 1);
    __syncthreads();
    for (int i = tid; i < NB; i += THREADS) pc[i * B1 + blk] = hist[i];
}

__global__ void k_s1(int* __restrict__ pc, int* __restrict__ bsums, int total) {
    __shared__ int s[1024];
    int t = threadIdx.x;
    int idx = blockIdx.x * 1024 + t;
    int v = (idx < total) ? pc[idx] : 0;
    s[t] = v;
    __syncthreads();
    for (int o = 1; o < 1024; o <<= 1) {
        int x = (t >= (unsigned)o) ? s[t - o] : 0;
        __syncthreads();
        s[t] += x;
        __syncthreads();
    }
    if (idx < total) pc[idx] = s[t] - v;           // exclusive within block
    if (t == 1023) bsums[blockIdx.x] = s[1023];    // block total
}

__global__ void k_s2(int* __restrict__ bsums, int nb) {
    __shared__ int s[128];
    int t = threadIdx.x;
    int v = (t < nb) ? bsums[t] : 0;
    s[t] = v;
    __syncthreads();
    for (int o = 1; o < 128; o <<= 1) {
        int x = (t >= (unsigned)o) ? s[t - o] : 0;
        __syncthreads();
        s[t] += x;
        __syncthreads();
    }
    if (t < nb) bsums[t] = s[t] - v;
}

__global__ void k_p2(const int* __restrict__ src, const int* __restrict__ dst,
                     const int* __restrict__ pc, const int* __restrict__ bsx,
                     unsigned long long* __restrict__ part, int E, int NB, int chunk) {
    __shared__ int cur[512];
    int tid = threadIdx.x, blk = blockIdx.x;
    for (int i = tid; i < NB; i += THREADS) {
        int idx = i * B1 + blk;
        cur[i] = pc[idx] + bsx[idx >> 10];
    }
    __syncthreads();
    int e0 = blk * chunk;
    int e1 = e0 + chunk; if (e1 > E) e1 = E;
    for (int e = e0 + tid; e < e1; e += THREADS) {
        int d = dst[e], sv = src[e];
        int pos = atomicAdd(&cur[d >> 8], 1);      // LDS atomic
        part[pos] = ((unsigned long long)(unsigned)d << 32) | (unsigned)sv;
    }
}

// k_p3 also zeroes cnt[] (node-mapped), replacing a host-side memset.
__global__ void k_p3(const unsigned long long* __restrict__ part,
                     const int* __restrict__ pc, const int* __restrict__ bsx,
                     int* __restrict__ off, float* __restrict__ dinv,
                     int* __restrict__ csr, float* __restrict__ cnt,
                     int E, int NB, int n) {
    __shared__ int hist[256];
    __shared__ int so[256];
    int b = blockIdx.x, t = threadIdx.x;
    int i0 = b * B1, i1 = (b + 1) * B1;
    int base = pc[i0] + bsx[i0 >> 10];
    int end  = (b + 1 < NB) ? (pc[i1] + bsx[i1 >> 10]) : E;
    hist[t] = 0;
    __syncthreads();
    for (int e = base + t; e < end; e += THREADS)
        atomicAdd(&hist[(int)(part[e] >> 32) & 255], 1);
    __syncthreads();
    int h = hist[t];
    so[t] = h;
    __syncthreads();
    for (int o = 1; o < 256; o <<= 1) {
        int x = (t >= (unsigned)o) ? so[t - o] : 0;
        __syncthreads();
        so[t] += x;
        __syncthreads();
    }
    int ex = so[t] - h;                            // exclusive within bucket
    int node = (b << 8) + t;
    if (node < n) {
        off[node]  = base + ex;
        dinv[node] = rsqrtf((float)h + 1.0f);
        cnt[node]  = 0.0f;                         // fused memset
        if (node == n - 1) off[n] = E;
    }
    __syncthreads();
    so[t] = base + ex;                             // cursors
    __syncthreads();
    for (int e = base + t; e < end; e += THREADS) {
        unsigned long long p = part[e];
        int pos = atomicAdd(&so[(int)(p >> 32) & 255], 1);   // LDS atomic
        csr[pos] = (int)(p & 0xffffffffu);
    }
}

// =================== MFMA dense GEMM: C = (X @ W) * dinv -> bf16 ===========
template<int KTILES, bool XF32>
__global__ __launch_bounds__(THREADS) void
k_mgemm(const float* __restrict__ Xf, const ushort* __restrict__ Xh,
        const float* __restrict__ W, const float* __restrict__ dinv,
        ushort* __restrict__ C, int n,
        const int* __restrict__ dict, float* __restrict__ cnt,
        float* __restrict__ pool16, int nGemm, int nCnt, int nZero) {
    int tid = threadIdx.x;
    if ((int)blockIdx.x >= nGemm) {
        int rb = (int)blockIdx.x - nGemm;
        if (rb < nCnt) {
            // ---- cnt role: dict histogram (hidden under the GEMM) ----
            int stride = nCnt * THREADS;
            for (int i = rb * THREADS + tid; i < n; i += stride)
                atomicAdd(&cnt[dict[i]], 1.0f);
        } else {
            // ---- zero role: pool16 = 0 (replaces host memset) ----
            int zb = rb - nCnt;
            uint4* p4 = (uint4*)pool16;
            int tot = n * 4;                 // n*16 floats = n*4 uint4
            int stride = nZero * THREADS;
            uint4 z = {0, 0, 0, 0};
            for (int i = zb * THREADS + tid; i < tot; i += stride) p4[i] = z;
        }
        return;
    }
    __shared__ ushort wfrag[KTILES * 2048];   // KTILES*4 tiles * 64 lanes * 8 bf16
    __shared__ float hrow[4][16 * 64];        // per-wave repack buffer (16 KB)
    const int FIN = KTILES * 32;
    for (int i = tid; i < FIN * 64; i += THREADS) {
        int k = i >> 6, c = i & 63;           // W[k][c], row-major [FIN][64]
        int kk = k >> 5, G = (k >> 3) & 3, e = k & 7;
        int t = c >> 4, c16 = c & 15;
        wfrag[(((kk * 4 + t) * 64) + G * 16 + c16) * 8 + e] = f2bf(W[i]);
    }
    __syncthreads();
    int wslot = tid >> 6, lane = tid & 63;
    int G = lane >> 4, c16 = lane & 15;
    int n0 = blockIdx.x * 64 + wslot * 16;
    int xrow = n0 + c16; if (xrow >= n) xrow = n - 1;
    const bf16x8* wf = (const bf16x8*)wfrag;
    f32x4 acc0 = {0, 0, 0, 0}, acc1 = acc0, acc2 = acc0, acc3 = acc0;
    #pragma unroll
    for (int kk = 0; kk < KTILES; ++kk) {
        bf16x8 a;
        if (XF32) {
            const float* xp = Xf + (size_t)xrow * FIN + kk * 32 + G * 8;
            float4 xa = *(const float4*)xp;
            float4 xb = *(const float4*)(xp + 4);
            a[0] = (short)f2bf(xa.x); a[1] = (short)f2bf(xa.y);
            a[2] = (short)f2bf(xa.z); a[3] = (short)f2bf(xa.w);
            a[4] = (short)f2bf(xb.x); a[5] = (short)f2bf(xb.y);
            a[6] = (short)f2bf(xb.z); a[7] = (short)f2bf(xb.w);
        } else {
            a = *(const bf16x8*)(Xh + (size_t)xrow * FIN + kk * 32 + G * 8);
        }
        bf16x8 b0 = wf[(kk * 4 + 0) * 64 + lane];
        bf16x8 b1 = wf[(kk * 4 + 1) * 64 + lane];
        bf16x8 b2 = wf[(kk * 4 + 2) * 64 + lane];
        bf16x8 b3 = wf[(kk * 4 + 3) * 64 + lane];
        acc0 = __builtin_amdgcn_mfma_f32_16x16x32_bf16(a, b0, acc0, 0, 0, 0);
        acc1 = __builtin_amdgcn_mfma_f32_16x16x32_bf16(a, b1, acc1, 0, 0, 0);
        acc2 = __builtin_amdgcn_mfma_f32_16x16x32_bf16(a, b2, acc2, 0, 0, 0);
        acc3 = __builtin_amdgcn_mfma_f32_16x16x32_bf16(a, b3, acc3, 0, 0, 0);
    }
    // ---- epilogue: D row=G*4+r, col=c16+16t; dinv scale; LDS repack ----
    int vm = n - n0; if (vm > 16) vm = 16;    // may be <=0 for tail waves
    float* hr = &hrow[wslot][0];
    #pragma unroll
    for (int r = 0; r < 4; ++r) {
        int rr = G * 4 + r;
        if (rr < vm) {
            float dn = dinv[n0 + rr];
            hr[rr * 64 + c16]      = acc0[r] * dn;
            hr[rr * 64 + c16 + 16] = acc1[r] * dn;
            hr[rr * 64 + c16 + 32] = acc2[r] * dn;
            hr[rr * 64 + c16 + 48] = acc3[r] * dn;
        }
    }
    asm volatile("" ::: "memory");            // same-wave LDS RAW ordering
    int prow = lane >> 2, pseg = lane & 3;    // 16 rows x 4 col-segments
    if (prow < vm) {
        const float* hp = hr + prow * 64 + pseg * 16;
        float4 f0 = *(const float4*)(hp + 0);
        float4 f1 = *(const float4*)(hp + 4);
        float4 f2 = *(const float4*)(hp + 8);
        float4 f3 = *(const float4*)(hp + 12);
        uint4 o0, o1;
        o0.x = pack2(f0.x, f0.y); o0.y = pack2(f0.z, f0.w);
        o0.z = pack2(f1.x, f1.y); o0.w = pack2(f1.z, f1.w);
        o1.x = pack2(f2.x, f2.y); o1.y = pack2(f2.z, f2.w);
        o1.z = pack2(f3.x, f3.y); o1.w = pack2(f3.z, f3.w);
        ushort* op = C + ((size_t)(n0 + prow) << 6) + pseg * 16;
        *(uint4*)(op)     = o0;
        *(uint4*)(op + 8) = o1;
    }
}

// =================== MFMA aggregation (3-deep rotation, round-9 proven) =====
__device__ inline void tr_mfma4(unsigned la, const bf16x8& a,
                                f32x4& o0, f32x4& o1, f32x4& o2, f32x4& o3) {
    u32x2 r0, r1, r2, r3, r4, r5, r6, r7;
    asm volatile(
        "s_waitcnt lgkmcnt(0)\n\t"
        "ds_read_b64_tr_b16 %0, %8 offset:0\n\t"
        "ds_read_b64_tr_b16 %1, %8 offset:512\n\t"
        "ds_read_b64_tr_b16 %2, %8 offset:1024\n\t"
        "ds_read_b64_tr_b16 %3, %8 offset:1536\n\t"
        "ds_read_b64_tr_b16 %4, %8 offset:2048\n\t"
        "ds_read_b64_tr_b16 %5, %8 offset:2560\n\t"
        "ds_read_b64_tr_b16 %6, %8 offset:3072\n\t"
        "ds_read_b64_tr_b16 %7, %8 offset:3584\n\t"
        "s_waitcnt lgkmcnt(0)"
        : "=&v"(r0), "=&v"(r1), "=&v"(r2), "=&v"(r3),
          "=&v"(r4), "=&v"(r5), "=&v"(r6), "=&v"(r7)
        : "v"(la) : "memory");
    __builtin_amdgcn_sched_barrier(0);       // keep MFMAs after the waitcnt
    union { u32x2 d[2]; bf16x8 v; } b0, b1, b2, b3;
    b0.d[0] = r0; b0.d[1] = r1; b1.d[0] = r2; b1.d[1] = r3;
    b2.d[0] = r4; b2.d[1] = r5; b3.d[0] = r6; b3.d[1] = r7;
    o0 = __builtin_amdgcn_mfma_f32_16x16x32_bf16(a, b0.v, o0, 0, 0, 0);
    o1 = __builtin_amdgcn_mfma_f32_16x16x32_bf16(a, b1.v, o1, 0, 0, 0);
    o2 = __builtin_amdgcn_mfma_f32_16x16x32_bf16(a, b2.v, o2, 0, 0, 0);
    o3 = __builtin_amdgcn_mfma_f32_16x16x32_bf16(a, b3.v, o3, 0, 0, 0);
}

// LAYER 1: relu(acc*dinv + b1) -> bf16 rows (coalesced via LDS repack)
// LAYER 2: relu(acc*dinv + b2) -> FC(64->16) -> atomicAdd pool16[dict[node]]
template<int LAYER>
__global__ __launch_bounds__(THREADS) void
k_agg(const ushort* __restrict__ H, const int* __restrict__ csr,
      const int* __restrict__ off, const float* __restrict__ dinv,
      const float* __restrict__ bias, ushort* __restrict__ outB,
      const float* __restrict__ Wfc, const int* __restrict__ dict,
      float* __restrict__ pool16, int n) {
    __shared__ ushort cbuf[4][2048];          // 4KB per wave, per-wave private
    __shared__ float wt[16 * 65];             // Wfc^T (LAYER2)
    int tid = threadIdx.x;
    if (LAYER == 2) {
        for (int i = tid; i < 64 * 16; i += THREADS) {
            int cc = i >> 4, r = i & 15;
            wt[r * 65 + cc] = Wfc[i];         // wt[r][cc] = Wfc[cc*16+r]
        }
        __syncthreads();                      // all threads reach this
    }
    int wslot = tid >> 6, lane = tid & 63;
    int gw = blockIdx.x * 4 + wslot;
    int n0 = gw << 4;
    if (n0 >= n) return;                      // after barrier: safe
    int G = lane >> 4, c16 = lane & 15;
    int g8 = lane >> 3, q = lane & 7;
    ushort* wbuf = &cbuf[wslot][0];
    unsigned lbase = (unsigned)(size_t)wbuf;  // LDS byte offset
    int vm = n - n0; if (vm > 16) vm = 16;
    int sA = 0, eA = 0;
    if (c16 < vm) { sA = off[n0 + c16]; eA = off[n0 + c16 + 1]; }
    int base0   = __shfl(sA, 0);
    int baseEnd = __shfl(eA, vm - 1);
    unsigned rng = (unsigned)(eA - sA);
    int sb0 = (q >> 1) * 512 + (g8 >> 2) * 256 + (g8 & 3) * 16 + (q & 1) * 8;
    unsigned la = lbase + (unsigned)lane * 8; // tr-read base (bytes)
    f32x4 acc0 = {0, 0, 0, 0}, acc1 = acc0, acc2 = acc0, acc3 = acc0;

    // 3-deep chunk pipeline: c0 = current, c1 = +32, c2 = +64 (in flight)
    uint4 c0[4], c1[4], c2[4];
    #pragma unroll
    for (int it = 0; it < 4; ++it) {
        uint4 v = {0, 0, 0, 0};
        int k = base0 + it * 8 + g8;
        if (k < baseEnd) {
            int e = csr[k];
            v = *(const uint4*)(H + ((size_t)e << 6) + q * 8);
        }
        c0[it] = v;
    }
    #pragma unroll
    for (int it = 0; it < 4; ++it) {
        uint4 v = {0, 0, 0, 0};
        int k = base0 + 32 + it * 8 + g8;
        if (k < baseEnd) {
            int e = csr[k];
            v = *(const uint4*)(H + ((size_t)e << 6) + q * 8);
        }
        c1[it] = v;
    }
    for (int base = base0; base < baseEnd; base += 32) {
        #pragma unroll
        for (int it = 0; it < 4; ++it) {      // prefetch 2 chunks ahead
            uint4 v = {0, 0, 0, 0};
            int k = base + 64 + it * 8 + g8;
            if (k < baseEnd) {
                int e = csr[k];
                v = *(const uint4*)(H + ((size_t)e << 6) + q * 8);
            }
            c2[it] = v;
        }
        #pragma unroll
        for (int it = 0; it < 4; ++it)        // stage current chunk
            *(uint4*)(wbuf + sb0 + it * 64) = c0[it];
        int kb = base - sA;                   // indicator: base+k in [sA,eA)
        bf16x8 a;
        #pragma unroll
        for (int e2 = 0; e2 < 8; ++e2)
            a[e2] = ((unsigned)(G * 8 + e2 + kb) < rng) ? (short)0x3F80 : (short)0;
        tr_mfma4(la, a, acc0, acc1, acc2, acc3);
        #pragma unroll
        for (int it = 0; it < 4; ++it) { c0[it] = c1[it]; c1[it] = c2[it]; }
    }
    {   // self-loop chunk: rows 0..15 = H[n0..n0+15], A = identity
        #pragma unroll
        for (int it = 0; it < 4; ++it) {
            uint4 v = {0, 0, 0, 0};
            int k = it * 8 + g8;
            if (it < 2 && k < vm)
                v = *(const uint4*)(H + ((size_t)(n0 + k) << 6) + q * 8);
            *(uint4*)(wbuf + sb0 + it * 64) = v;
        }
        bf16x8 a;
        #pragma unroll
        for (int e2 = 0; e2 < 8; ++e2)
            a[e2] = ((G * 8 + e2) == c16) ? (short)0x3F80 : (short)0;
        tr_mfma4(la, a, acc0, acc1, acc2, acc3);
    }
    // ---- epilogue: D layout col=lane&15 (=c16), row=G*4+r ----
    float* hrow = (float*)wbuf;               // 16x64 f32, aliases staging buf
    float bv0 = bias[c16], bv1 = bias[c16 + 16],
          bv2 = bias[c16 + 32], bv3 = bias[c16 + 48];
    #pragma unroll
    for (int r = 0; r < 4; ++r) {
        int rr = G * 4 + r;
        if (rr < vm) {
            float dn = dinv[n0 + rr];
            float v0 = fmaxf(acc0[r] * dn + bv0, 0.f);
            float v1 = fmaxf(acc1[r] * dn + bv1, 0.f);
            float v2 = fmaxf(acc2[r] * dn + bv2, 0.f);
            float v3 = fmaxf(acc3[r] * dn + bv3, 0.f);
            hrow[rr * 64 + c16]      = v0;
            hrow[rr * 64 + c16 + 16] = v1;
            hrow[rr * 64 + c16 + 32] = v2;
            hrow[rr * 64 + c16 + 48] = v3;
        }
    }
    asm volatile("" ::: "memory");            // order hrow writes vs reads
    if (LAYER == 1) {
        int prow = lane >> 2, pseg = lane & 3;   // 16 rows x 4 col-segments
        if (prow < vm) {
            const float* hp = hrow + prow * 64 + pseg * 16;
            float4 f0 = *(const float4*)(hp + 0);
            float4 f1 = *(const float4*)(hp + 4);
            float4 f2 = *(const float4*)(hp + 8);
            float4 f3 = *(const float4*)(hp + 12);
            uint4 o0, o1;
            o0.x = pack2(f0.x, f0.y); o0.y = pack2(f0.z, f0.w);
            o0.z = pack2(f1.x, f1.y); o0.w = pack2(f1.z, f1.w);
            o1.x = pack2(f2.x, f2.y); o1.y = pack2(f2.z, f2.w);
            o1.z = pack2(f3.x, f3.y); o1.w = pack2(f3.z, f3.w);
            ushort* op = outB + ((size_t)(n0 + prow) << 6) + pseg * 16;
            *(uint4*)(op)     = o0;
            *(uint4*)(op + 8) = o1;
        }
    } else {
        int r16 = c16;                        // class index; G = col quarter
        for (int m = 0; m < vm; ++m) {
            const float* hm = hrow + m * 64 + G * 16;
            const float* wr = wt + r16 * 65 + G * 16;
            float p = 0.f;
            #pragma unroll
            for (int i = 0; i < 16; ++i) p = fmaf(hm[i], wr[i], p);
            p += __shfl_xor(p, 16);
            p += __shfl_xor(p, 32);
            if (G == 0)
                atomicAdd(&pool16[(size_t)dict[n0 + m] * 16 + r16], p);
        }
    }
}

// ---------- mean + bias + log_softmax over 16 classes ----------
__global__ void k_final16(const float* __restrict__ pool16, const float* __restrict__ cnt,
                          const float* __restrict__ bfc, float* __restrict__ out, int n) {
    int tid = threadIdx.x;
    int nl = tid >> 4, lane = tid & 15;
    int node = blockIdx.x * 16 + nl;
    if (node >= n) return;
    float inv = 1.0f / fmaxf(cnt[node], 1.0f);
    float acc = pool16[(size_t)node * 16 + lane] * inv + bfc[lane];
    float m = acc;
    for (int o = 8; o; o >>= 1) m = fmaxf(m, __shfl_xor(m, o, 16));
    float ex = __expf(acc - m);
    float s = ex;
    for (int o = 8; o; o >>= 1) s += __shfl_xor(s, o, 16);
    out[(size_t)node * 16 + lane] = acc - m - __logf(s);
}

extern "C" void kernel_launch(void* const* d_in, const int* in_sizes, int n_in,
                              void* d_out, int out_size, void* d_ws, size_t ws_size,
                              hipStream_t stream) {
    const float* x    = (const float*)d_in[0];
    const int*   ei   = (const int*)d_in[1];
    const int*   dict = (const int*)d_in[2];
    const float* W1   = (const float*)d_in[3];
    const float* b1   = (const float*)d_in[4];
    const float* W2   = (const float*)d_in[5];
    const float* b2   = (const float*)d_in[6];
    const float* Wfc  = (const float*)d_in[7];
    const float* bfc  = (const float*)d_in[8];

    const int N  = in_sizes[2];          // 100000
    const int E  = in_sizes[1] / 2;      // 1600000
    const int IN = in_sizes[0] / N;      // 128
    const int* src = ei;
    const int* dst = ei + E;

    // workspace layout (~40 MB, round-4 proven plan)
    ushort* bufA = (ushort*)d_ws;                        // N*64 bf16
    ushort* bufB = bufA + (size_t)N * 64;                // N*64 bf16
    unsigned long long* part = (unsigned long long*)bufB;  // E u64 (alias bufB)
    float* dinv    = (float*)(bufB + (size_t)N * 64);    // N
    float* cnt     = dinv + N;                           // N
    int*   off     = (int*)(cnt + N);                    // N+1
    int*   pcounts = off + (N + 1);                      // NB*B1
    const int NB     = (N + 255) >> 8;                   // 391
    const int pcsize = NB * B1;                          // 100096
    int*   bsums   = pcounts + pcsize;                   // 128
    int*   csr     = bsums + 128;                        // E
    float* pool16  = (float*)(csr + E);                  // N*16

    const int gTile = (N + 63) / 64;                     // 1563
    const int gRows = (N + 15) / 16;                     // 6250
    const int nCnt  = 256;
    const int nZero = 256;
    const int chunk = (E + B1 - 1) / B1;                 // 6250
    const int nS1   = (pcsize + 1023) >> 10;             // 98
    const int gAgg  = ((N + 15) / 16 + 3) / 4;           // 1563 (4 waves/block)

    // CSR build: LDS counting sort (no global atomics); p3 also zeroes cnt
    k_p1<<<B1, THREADS, 0, stream>>>(dst, pcounts, E, NB, chunk);
    k_s1<<<nS1, 1024, 0, stream>>>(pcounts, bsums, pcsize);
    k_s2<<<1, 128, 0, stream>>>(bsums, nS1);
    k_p2<<<B1, THREADS, 0, stream>>>(src, dst, pcounts, bsums, part, E, NB, chunk);
    k_p3<<<NB, THREADS, 0, stream>>>(part, pcounts, bsums, off, dinv, csr, cnt,
                                     E, NB, N);

    // GEMM1 (MFMA): bufA = bf16((x@W1)*dinv)  (+ cnt histogram + pool16 zero)
    k_mgemm<4, true><<<gTile + nCnt + nZero, THREADS, 0, stream>>>(
        x, nullptr, W1, dinv, bufA, N, dict, cnt, pool16, gTile, nCnt, nZero);

    // layer 1 MFMA aggregation: bufB = bf16(relu(dn*(sum+self)+b1))
    k_agg<1><<<gAgg, THREADS, 0, stream>>>(bufA, csr, off, dinv, b1, bufB,
                                           nullptr, nullptr, nullptr, N);

    // GEMM2 (MFMA): bufA = bf16((bufB@W2)*dinv); then agg2
    k_mgemm<2, false><<<gTile, THREADS, 0, stream>>>(
        nullptr, bufB, W2, dinv, bufA, N, nullptr, nullptr, nullptr, gTile, 0, 0);
    k_agg<2><<<gAgg, THREADS, 0, stream>>>(bufA, csr, off, dinv, b2, nullptr,
                                           Wfc, dict, pool16, N);

    // mean + bias + log_softmax
    k_final16<<<gRows, THREADS, 0, stream>>>(pool16, cnt, bfc, (float*)d_out, N);
}

// Round 12
// 269.796 us; speedup vs baseline: 1.1816x; 1.0427x over previous
//
#include <hip/hip_runtime.h>

#define THREADS 256
#define B1 256          // partition blocks for P1/P2 (edge chunks)

typedef __attribute__((ext_vector_type(8))) short bf16x8;   // 8 bf16 (4 VGPR)
typedef __attribute__((ext_vector_type(4))) float f32x4;
typedef __attribute__((ext_vector_type(2))) unsigned int u32x2;

// ---- bf16 helpers ----
__device__ inline ushort f2bf(float v) {
    union { float f; unsigned u; } a; a.f = v;
    unsigned r = a.u + 0x7fff + ((a.u >> 16) & 1);
    return (ushort)(r >> 16);
}
__device__ inline unsigned pack2(float a, float b) {
    return (unsigned)f2bf(a) | ((unsigned)f2bf(b) << 16);
}

// =================== CSR build (round-4 proven version) =====================

__global__ void k_p1(const int* __restrict__ dst, int* __restrict__ pc,
                     int E, int NB, int chunk) {
    __shared__ int hist[512];
    int tid = threadIdx.x, blk = blockIdx.x;
    for (int i = tid; i < NB; i += THREADS) hist[i] = 0;
    __syncthreads();
    int e0 = blk * chunk;
    int e1 = e0 + chunk; if (e1 > E) e1 = E;
    for (int e = e0 + tid; e < e1; e += THREADS)
        atomicAdd(&hist[dst[e] >> 8], 1);
    __syncthreads();
    for (int i = tid; i < NB; i += THREADS) pc[i * B1 + blk] = hist[i];
}

__global__ void k_s1(int* __restrict__ pc, int* __restrict__ bsums, int total) {
    __shared__ int s[1024];
    int t = threadIdx.x;
    int idx = blockIdx.x * 1024 + t;
    int v = (idx < total) ? pc[idx] : 0;
    s[t] = v;
    __syncthreads();
    for (int o = 1; o < 1024; o <<= 1) {
        int x = (t >= (unsigned)o) ? s[t - o] : 0;
        __syncthreads();
        s[t] += x;
        __syncthreads();
    }
    if (idx < total) pc[idx] = s[t] - v;           // exclusive within block
    if (t == 1023) bsums[blockIdx.x] = s[1023];    // block total
}

__global__ void k_s2(int* __restrict__ bsums, int nb) {
    __shared__ int s[128];
    int t = threadIdx.x;
    int v = (t < nb) ? bsums[t] : 0;
    s[t] = v;
    __syncthreads();
    for (int o = 1; o < 128; o <<= 1) {
        int x = (t >= (unsigned)o) ? s[t - o] : 0;
        __syncthreads();
        s[t] += x;
        __syncthreads();
    }
    if (t < nb) bsums[t] = s[t] - v;
}

__global__ void k_p2(const int* __restrict__ src, const int* __restrict__ dst,
                     const int* __restrict__ pc, const int* __restrict__ bsx,
                     unsigned long long* __restrict__ part, int E, int NB, int chunk) {
    __shared__ int cur[512];
    int tid = threadIdx.x, blk = blockIdx.x;
    for (int i = tid; i < NB; i += THREADS) {
        int idx = i * B1 + blk;
        cur[i] = pc[idx] + bsx[idx >> 10];
    }
    __syncthreads();
    int e0 = blk * chunk;
    int e1 = e0 + chunk; if (e1 > E) e1 = E;
    for (int e = e0 + tid; e < e1; e += THREADS) {
        int d = dst[e], sv = src[e];
        int pos = atomicAdd(&cur[d >> 8], 1);      // LDS atomic
        part[pos] = ((unsigned long long)(unsigned)d << 32) | (unsigned)sv;
    }
}

// k_p3 also zeroes cnt[] (node-mapped), replacing a host-side memset.
__global__ void k_p3(const unsigned long long* __restrict__ part,
                     const int* __restrict__ pc, const int* __restrict__ bsx,
                     int* __restrict__ off, float* __restrict__ dinv,
                     int* __restrict__ csr, float* __restrict__ cnt,
                     int E, int NB, int n) {
    __shared__ int hist[256];
    __shared__ int so[256];
    int b = blockIdx.x, t = threadIdx.x;
    int i0 = b * B1, i1 = (b + 1) * B1;
    int base = pc[i0] + bsx[i0 >> 10];
    int end  = (b + 1 < NB) ? (pc[i1] + bsx[i1 >> 10]) : E;
    hist[t] = 0;
    __syncthreads();
    for (int e = base + t; e < end; e += THREADS)
        atomicAdd(&hist[(int)(part[e] >> 32) & 255], 1);
    __syncthreads();
    int h = hist[t];
    so[t] = h;
    __syncthreads();
    for (int o = 1; o < 256; o <<= 1) {
        int x = (t >= (unsigned)o) ? so[t - o] : 0;
        __syncthreads();
        so[t] += x;
        __syncthreads();
    }
    int ex = so[t] - h;                            // exclusive within bucket
    int node = (b << 8) + t;
    if (node < n) {
        off[node]  = base + ex;
        dinv[node] = rsqrtf((float)h + 1.0f);
        cnt[node]  = 0.0f;                         // fused memset
        if (node == n - 1) off[n] = E;
    }
    __syncthreads();
    so[t] = base + ex;                             // cursors
    __syncthreads();
    for (int e = base + t; e < end; e += THREADS) {
        unsigned long long p = part[e];
        int pos = atomicAdd(&so[(int)(p >> 32) & 255], 1);   // LDS atomic
        csr[pos] = (int)(p & 0xffffffffu);
    }
}

// =================== MFMA dense GEMM: C = (X @ W) * dinv -> bf16 ===========
template<int KTILES, bool XF32>
__global__ __launch_bounds__(THREADS) void
k_mgemm(const float* __restrict__ Xf, const ushort* __restrict__ Xh,
        const float* __restrict__ W, const float* __restrict__ dinv,
        ushort* __restrict__ C, int n,
        const int* __restrict__ dict, float* __restrict__ cnt,
        float* __restrict__ pool16, int nGemm, int nCnt, int nZero) {
    int tid = threadIdx.x;
    if ((int)blockIdx.x >= nGemm) {
        int rb = (int)blockIdx.x - nGemm;
        if (rb < nCnt) {
            // ---- cnt role: dict histogram (hidden under the GEMM) ----
            int stride = nCnt * THREADS;
            for (int i = rb * THREADS + tid; i < n; i += stride)
                atomicAdd(&cnt[dict[i]], 1.0f);
        } else {
            // ---- zero role: pool16 = 0 (replaces host memset) ----
            int zb = rb - nCnt;
            uint4* p4 = (uint4*)pool16;
            int tot = n * 4;                 // n*16 floats = n*4 uint4
            int stride = nZero * THREADS;
            uint4 z = {0, 0, 0, 0};
            for (int i = zb * THREADS + tid; i < tot; i += stride) p4[i] = z;
        }
        return;
    }
    __shared__ ushort wfrag[KTILES * 2048];   // KTILES*4 tiles * 64 lanes * 8 bf16
    __shared__ float hrow[4][16 * 64];        // per-wave repack buffer (16 KB)
    const int FIN = KTILES * 32;
    for (int i = tid; i < FIN * 64; i += THREADS) {
        int k = i >> 6, c = i & 63;           // W[k][c], row-major [FIN][64]
        int kk = k >> 5, G = (k >> 3) & 3, e = k & 7;
        int t = c >> 4, c16 = c & 15;
        wfrag[(((kk * 4 + t) * 64) + G * 16 + c16) * 8 + e] = f2bf(W[i]);
    }
    __syncthreads();
    int wslot = tid >> 6, lane = tid & 63;
    int G = lane >> 4, c16 = lane & 15;
    int n0 = blockIdx.x * 64 + wslot * 16;
    int xrow = n0 + c16; if (xrow >= n) xrow = n - 1;
    const bf16x8* wf = (const bf16x8*)wfrag;
    f32x4 acc0 = {0, 0, 0, 0}, acc1 = acc0, acc2 = acc0, acc3 = acc0;
    #pragma unroll
    for (int kk = 0; kk < KTILES; ++kk) {
        bf16x8 a;
        if (XF32) {
            const float* xp = Xf + (size_t)xrow * FIN + kk * 32 + G * 8;
            float4 xa = *(const float4*)xp;
            float4 xb = *(const float4*)(xp + 4);
            a[0] = (short)f2bf(xa.x); a[1] = (short)f2bf(xa.y);
            a[2] = (short)f2bf(xa.z); a[3] = (short)f2bf(xa.w);
            a[4] = (short)f2bf(xb.x); a[5] = (short)f2bf(xb.y);
            a[6] = (short)f2bf(xb.z); a[7] = (short)f2bf(xb.w);
        } else {
            a = *(const bf16x8*)(Xh + (size_t)xrow * FIN + kk * 32 + G * 8);
        }
        bf16x8 b0 = wf[(kk * 4 + 0) * 64 + lane];
        bf16x8 b1 = wf[(kk * 4 + 1) * 64 + lane];
        bf16x8 b2 = wf[(kk * 4 + 2) * 64 + lane];
        bf16x8 b3 = wf[(kk * 4 + 3) * 64 + lane];
        acc0 = __builtin_amdgcn_mfma_f32_16x16x32_bf16(a, b0, acc0, 0, 0, 0);
        acc1 = __builtin_amdgcn_mfma_f32_16x16x32_bf16(a, b1, acc1, 0, 0, 0);
        acc2 = __builtin_amdgcn_mfma_f32_16x16x32_bf16(a, b2, acc2, 0, 0, 0);
        acc3 = __builtin_amdgcn_mfma_f32_16x16x32_bf16(a, b3, acc3, 0, 0, 0);
    }
    // ---- epilogue: D row=G*4+r, col=c16+16t; dinv scale; LDS repack ----
    int vm = n - n0; if (vm > 16) vm = 16;    // may be <=0 for tail waves
    float* hr = &hrow[wslot][0];
    #pragma unroll
    for (int r = 0; r < 4; ++r) {
        int rr = G * 4 + r;
        if (rr < vm) {
            float dn = dinv[n0 + rr];
            hr[rr * 64 + c16]      = acc0[r] * dn;
            hr[rr * 64 + c16 + 16] = acc1[r] * dn;
            hr[rr * 64 + c16 + 32] = acc2[r] * dn;
            hr[rr * 64 + c16 + 48] = acc3[r] * dn;
        }
    }
    asm volatile("" ::: "memory");            // same-wave LDS RAW ordering
    int prow = lane >> 2, pseg = lane & 3;    // 16 rows x 4 col-segments
    if (prow < vm) {
        const float* hp = hr + prow * 64 + pseg * 16;
        float4 f0 = *(const float4*)(hp + 0);
        float4 f1 = *(const float4*)(hp + 4);
        float4 f2 = *(const float4*)(hp + 8);
        float4 f3 = *(const float4*)(hp + 12);
        uint4 o0, o1;
        o0.x = pack2(f0.x, f0.y); o0.y = pack2(f0.z, f0.w);
        o0.z = pack2(f1.x, f1.y); o0.w = pack2(f1.z, f1.w);
        o1.x = pack2(f2.x, f2.y); o1.y = pack2(f2.z, f2.w);
        o1.z = pack2(f3.x, f3.y); o1.w = pack2(f3.z, f3.w);
        ushort* op = C + ((size_t)(n0 + prow) << 6) + pseg * 16;
        *(uint4*)(op)     = o0;
        *(uint4*)(op + 8) = o1;
    }
}

// =================== MFMA aggregation (3-deep rotation, round-9 proven) =====
__device__ inline void tr_mfma4(unsigned la, const bf16x8& a,
                                f32x4& o0, f32x4& o1, f32x4& o2, f32x4& o3) {
    u32x2 r0, r1, r2, r3, r4, r5, r6, r7;
    asm volatile(
        "s_waitcnt lgkmcnt(0)\n\t"
        "ds_read_b64_tr_b16 %0, %8 offset:0\n\t"
        "ds_read_b64_tr_b16 %1, %8 offset:512\n\t"
        "ds_read_b64_tr_b16 %2, %8 offset:1024\n\t"
        "ds_read_b64_tr_b16 %3, %8 offset:1536\n\t"
        "ds_read_b64_tr_b16 %4, %8 offset:2048\n\t"
        "ds_read_b64_tr_b16 %5, %8 offset:2560\n\t"
        "ds_read_b64_tr_b16 %6, %8 offset:3072\n\t"
        "ds_read_b64_tr_b16 %7, %8 offset:3584\n\t"
        "s_waitcnt lgkmcnt(0)"
        : "=&v"(r0), "=&v"(r1), "=&v"(r2), "=&v"(r3),
          "=&v"(r4), "=&v"(r5), "=&v"(r6), "=&v"(r7)
        : "v"(la) : "memory");
    __builtin_amdgcn_sched_barrier(0);       // keep MFMAs after the waitcnt
    union { u32x2 d[2]; bf16x8 v; } b0, b1, b2, b3;
    b0.d[0] = r0; b0.d[1] = r1; b1.d[0] = r2; b1.d[1] = r3;
    b2.d[0] = r4; b2.d[1] = r5; b3.d[0] = r6; b3.d[1] = r7;
    o0 = __builtin_amdgcn_mfma_f32_16x16x32_bf16(a, b0.v, o0, 0, 0, 0);
    o1 = __builtin_amdgcn_mfma_f32_16x16x32_bf16(a, b1.v, o1, 0, 0, 0);
    o2 = __builtin_amdgcn_mfma_f32_16x16x32_bf16(a, b2.v, o2, 0, 0, 0);
    o3 = __builtin_amdgcn_mfma_f32_16x16x32_bf16(a, b3.v, o3, 0, 0, 0);
}

// LAYER 1: relu(acc*dinv + b1) = h1; FUSED GEMM2: bufB = bf16((h1@W2)*dinv)
// LAYER 2: relu(acc*dinv + b2) -> FC(64->16) -> atomicAdd pool16[dict[node]]
// wsrc = W2 (LAYER1, staged as MFMA B-fragments) or Wfc (LAYER2, wt table).
template<int LAYER>
__global__ __launch_bounds__(THREADS) void
k_agg(const ushort* __restrict__ H, const int* __restrict__ csr,
      const int* __restrict__ off, const float* __restrict__ dinv,
      const float* __restrict__ bias, ushort* __restrict__ outB,
      const float* __restrict__ wsrc, const int* __restrict__ dict,
      float* __restrict__ pool16, int n) {
    __shared__ ushort cbuf[4][2048];          // 4KB per wave, per-wave private
    __shared__ ushort extra[LAYER == 1 ? 4096 : 2080];  // W2 frags | Wfc^T
    int tid = threadIdx.x;
    if (LAYER == 1) {
        // stage W2 (64x64 row-major) as B-fragments, KTILES=2 (k_mgemm layout)
        for (int i = tid; i < 64 * 64; i += THREADS) {
            int k = i >> 6, c = i & 63;
            int kk = k >> 5, Gs = (k >> 3) & 3, e = k & 7;
            int t = c >> 4, cs = c & 15;
            extra[(((kk * 4 + t) * 64) + Gs * 16 + cs) * 8 + e] = f2bf(wsrc[i]);
        }
        __syncthreads();
    } else {
        float* wt = (float*)extra;            // wt[r][cc] = Wfc[cc*16+r]
        for (int i = tid; i < 64 * 16; i += THREADS) {
            int cc = i >> 4, r = i & 15;
            wt[r * 65 + cc] = wsrc[i];
        }
        __syncthreads();
    }
    int wslot = tid >> 6, lane = tid & 63;
    int gw = blockIdx.x * 4 + wslot;
    int n0 = gw << 4;
    if (n0 >= n) return;                      // after barrier: safe
    int G = lane >> 4, c16 = lane & 15;
    int g8 = lane >> 3, q = lane & 7;
    ushort* wbuf = &cbuf[wslot][0];
    unsigned lbase = (unsigned)(size_t)wbuf;  // LDS byte offset
    int vm = n - n0; if (vm > 16) vm = 16;
    int sA = 0, eA = 0;
    if (c16 < vm) { sA = off[n0 + c16]; eA = off[n0 + c16 + 1]; }
    int base0   = __shfl(sA, 0);
    int baseEnd = __shfl(eA, vm - 1);
    unsigned rng = (unsigned)(eA - sA);
    int sb0 = (q >> 1) * 512 + (g8 >> 2) * 256 + (g8 & 3) * 16 + (q & 1) * 8;
    unsigned la = lbase + (unsigned)lane * 8; // tr-read base (bytes)
    f32x4 acc0 = {0, 0, 0, 0}, acc1 = acc0, acc2 = acc0, acc3 = acc0;

    // 3-deep chunk pipeline: c0 = current, c1 = +32, c2 = +64 (in flight)
    uint4 c0[4], c1[4], c2[4];
    #pragma unroll
    for (int it = 0; it < 4; ++it) {
        uint4 v = {0, 0, 0, 0};
        int k = base0 + it * 8 + g8;
        if (k < baseEnd) {
            int e = csr[k];
            v = *(const uint4*)(H + ((size_t)e << 6) + q * 8);
        }
        c0[it] = v;
    }
    #pragma unroll
    for (int it = 0; it < 4; ++it) {
        uint4 v = {0, 0, 0, 0};
        int k = base0 + 32 + it * 8 + g8;
        if (k < baseEnd) {
            int e = csr[k];
            v = *(const uint4*)(H + ((size_t)e << 6) + q * 8);
        }
        c1[it] = v;
    }
    for (int base = base0; base < baseEnd; base += 32) {
        #pragma unroll
        for (int it = 0; it < 4; ++it) {      // prefetch 2 chunks ahead
            uint4 v = {0, 0, 0, 0};
            int k = base + 64 + it * 8 + g8;
            if (k < baseEnd) {
                int e = csr[k];
                v = *(const uint4*)(H + ((size_t)e << 6) + q * 8);
            }
            c2[it] = v;
        }
        #pragma unroll
        for (int it = 0; it < 4; ++it)        // stage current chunk
            *(uint4*)(wbuf + sb0 + it * 64) = c0[it];
        int kb = base - sA;                   // indicator: base+k in [sA,eA)
        bf16x8 a;
        #pragma unroll
        for (int e2 = 0; e2 < 8; ++e2)
            a[e2] = ((unsigned)(G * 8 + e2 + kb) < rng) ? (short)0x3F80 : (short)0;
        tr_mfma4(la, a, acc0, acc1, acc2, acc3);
        #pragma unroll
        for (int it = 0; it < 4; ++it) { c0[it] = c1[it]; c1[it] = c2[it]; }
    }
    {   // self-loop chunk: rows 0..15 = H[n0..n0+15], A = identity
        #pragma unroll
        for (int it = 0; it < 4; ++it) {
            uint4 v = {0, 0, 0, 0};
            int k = it * 8 + g8;
            if (it < 2 && k < vm)
                v = *(const uint4*)(H + ((size_t)(n0 + k) << 6) + q * 8);
            *(uint4*)(wbuf + sb0 + it * 64) = v;
        }
        bf16x8 a;
        #pragma unroll
        for (int e2 = 0; e2 < 8; ++e2)
            a[e2] = ((G * 8 + e2) == c16) ? (short)0x3F80 : (short)0;
        tr_mfma4(la, a, acc0, acc1, acc2, acc3);
    }
    // ---- epilogue: D layout col=lane&15 (=c16), row=G*4+r ----
    float* hrow = (float*)wbuf;               // 16x64 f32, aliases staging buf
    float bv0 = bias[c16], bv1 = bias[c16 + 16],
          bv2 = bias[c16 + 32], bv3 = bias[c16 + 48];
    #pragma unroll
    for (int r = 0; r < 4; ++r) {
        int rr = G * 4 + r;
        if (rr < vm) {
            float dn = dinv[n0 + rr];
            float v0 = fmaxf(acc0[r] * dn + bv0, 0.f);
            float v1 = fmaxf(acc1[r] * dn + bv1, 0.f);
            float v2 = fmaxf(acc2[r] * dn + bv2, 0.f);
            float v3 = fmaxf(acc3[r] * dn + bv3, 0.f);
            hrow[rr * 64 + c16]      = v0;
            hrow[rr * 64 + c16 + 16] = v1;
            hrow[rr * 64 + c16 + 32] = v2;
            hrow[rr * 64 + c16 + 48] = v3;
        }
    }
    asm volatile("" ::: "memory");            // order hrow writes vs reads
    if (LAYER == 1) {
        // ---- fused GEMM2: h2(16x64) = h1(hrow) @ W2; then *dinv -> bufB ----
        // A-fragments: lane holds A[row=c16][k=kk*32+G*8+e] = hrow[c16][k]
        const float* ap = hrow + c16 * 64 + G * 8;
        float4 xa = *(const float4*)(ap);
        float4 xb = *(const float4*)(ap + 4);
        float4 ya = *(const float4*)(ap + 32);
        float4 yb = *(const float4*)(ap + 36);
        bf16x8 a0, a1;
        a0[0] = (short)f2bf(xa.x); a0[1] = (short)f2bf(xa.y);
        a0[2] = (short)f2bf(xa.z); a0[3] = (short)f2bf(xa.w);
        a0[4] = (short)f2bf(xb.x); a0[5] = (short)f2bf(xb.y);
        a0[6] = (short)f2bf(xb.z); a0[7] = (short)f2bf(xb.w);
        a1[0] = (short)f2bf(ya.x); a1[1] = (short)f2bf(ya.y);
        a1[2] = (short)f2bf(ya.z); a1[3] = (short)f2bf(ya.w);
        a1[4] = (short)f2bf(yb.x); a1[5] = (short)f2bf(yb.y);
        a1[6] = (short)f2bf(yb.z); a1[7] = (short)f2bf(yb.w);
        const bf16x8* wf2 = (const bf16x8*)extra;
        f32x4 h0 = {0, 0, 0, 0}, h1v = h0, h2v = h0, h3v = h0;
        h0  = __builtin_amdgcn_mfma_f32_16x16x32_bf16(a0, wf2[0 * 64 + lane], h0, 0, 0, 0);
        h1v = __builtin_amdgcn_mfma_f32_16x16x32_bf16(a0, wf2[1 * 64 + lane], h1v, 0, 0, 0);
        h2v = __builtin_amdgcn_mfma_f32_16x16x32_bf16(a0, wf2[2 * 64 + lane], h2v, 0, 0, 0);
        h3v = __builtin_amdgcn_mfma_f32_16x16x32_bf16(a0, wf2[3 * 64 + lane], h3v, 0, 0, 0);
        h0  = __builtin_amdgcn_mfma_f32_16x16x32_bf16(a1, wf2[4 * 64 + lane], h0, 0, 0, 0);
        h1v = __builtin_amdgcn_mfma_f32_16x16x32_bf16(a1, wf2[5 * 64 + lane], h1v, 0, 0, 0);
        h2v = __builtin_amdgcn_mfma_f32_16x16x32_bf16(a1, wf2[6 * 64 + lane], h2v, 0, 0, 0);
        h3v = __builtin_amdgcn_mfma_f32_16x16x32_bf16(a1, wf2[7 * 64 + lane], h3v, 0, 0, 0);
        asm volatile("" ::: "memory");
        #pragma unroll
        for (int r = 0; r < 4; ++r) {
            int rr = G * 4 + r;
            if (rr < vm) {
                float dn = dinv[n0 + rr];
                hrow[rr * 64 + c16]      = h0[r] * dn;
                hrow[rr * 64 + c16 + 16] = h1v[r] * dn;
                hrow[rr * 64 + c16 + 32] = h2v[r] * dn;
                hrow[rr * 64 + c16 + 48] = h3v[r] * dn;
            }
        }
        asm volatile("" ::: "memory");
        int prow = lane >> 2, pseg = lane & 3;   // 16 rows x 4 col-segments
        if (prow < vm) {
            const float* hp = hrow + prow * 64 + pseg * 16;
            float4 f0 = *(const float4*)(hp + 0);
            float4 f1 = *(const float4*)(hp + 4);
            float4 f2 = *(const float4*)(hp + 8);
            float4 f3 = *(const float4*)(hp + 12);
            uint4 o0, o1;
            o0.x = pack2(f0.x, f0.y); o0.y = pack2(f0.z, f0.w);
            o0.z = pack2(f1.x, f1.y); o0.w = pack2(f1.z, f1.w);
            o1.x = pack2(f2.x, f2.y); o1.y = pack2(f2.z, f2.w);
            o1.z = pack2(f3.x, f3.y); o1.w = pack2(f3.z, f3.w);
            ushort* op = outB + ((size_t)(n0 + prow) << 6) + pseg * 16;
            *(uint4*)(op)     = o0;
            *(uint4*)(op + 8) = o1;
        }
    } else {
        const float* wt = (const float*)extra;
        int r16 = c16;                        // class index; G = col quarter
        for (int m = 0; m < vm; ++m) {
            const float* hm = hrow + m * 64 + G * 16;
            const float* wr = wt + r16 * 65 + G * 16;
            float p = 0.f;
            #pragma unroll
            for (int i = 0; i < 16; ++i) p = fmaf(hm[i], wr[i], p);
            p += __shfl_xor(p, 16);
            p += __shfl_xor(p, 32);
            if (G == 0)
                atomicAdd(&pool16[(size_t)dict[n0 + m] * 16 + r16], p);
        }
    }
}

// ---------- mean + bias + log_softmax over 16 classes ----------
__global__ void k_final16(const float* __restrict__ pool16, const float* __restrict__ cnt,
                          const float* __restrict__ bfc, float* __restrict__ out, int n) {
    int tid = threadIdx.x;
    int nl = tid >> 4, lane = tid & 15;
    int node = blockIdx.x * 16 + nl;
    if (node >= n) return;
    float inv = 1.0f / fmaxf(cnt[node], 1.0f);
    float acc = pool16[(size_t)node * 16 + lane] * inv + bfc[lane];
    float m = acc;
    for (int o = 8; o; o >>= 1) m = fmaxf(m, __shfl_xor(m, o, 16));
    float ex = __expf(acc - m);
    float s = ex;
    for (int o = 8; o; o >>= 1) s += __shfl_xor(s, o, 16);
    out[(size_t)node * 16 + lane] = acc - m - __logf(s);
}

extern "C" void kernel_launch(void* const* d_in, const int* in_sizes, int n_in,
                              void* d_out, int out_size, void* d_ws, size_t ws_size,
                              hipStream_t stream) {
    const float* x    = (const float*)d_in[0];
    const int*   ei   = (const int*)d_in[1];
    const int*   dict = (const int*)d_in[2];
    const float* W1   = (const float*)d_in[3];
    const float* b1   = (const float*)d_in[4];
    const float* W2   = (const float*)d_in[5];
    const float* b2   = (const float*)d_in[6];
    const float* Wfc  = (const float*)d_in[7];
    const float* bfc  = (const float*)d_in[8];

    const int N  = in_sizes[2];          // 100000
    const int E  = in_sizes[1] / 2;      // 1600000
    const int IN = in_sizes[0] / N;      // 128
    const int* src = ei;
    const int* dst = ei + E;

    // workspace layout (~40 MB, round-4 proven plan)
    ushort* bufA = (ushort*)d_ws;                        // N*64 bf16
    ushort* bufB = bufA + (size_t)N * 64;                // N*64 bf16
    unsigned long long* part = (unsigned long long*)bufB;  // E u64 (alias bufB)
    float* dinv    = (float*)(bufB + (size_t)N * 64);    // N
    float* cnt     = dinv + N;                           // N
    int*   off     = (int*)(cnt + N);                    // N+1
    int*   pcounts = off + (N + 1);                      // NB*B1
    const int NB     = (N + 255) >> 8;                   // 391
    const int pcsize = NB * B1;                          // 100096
    int*   bsums   = pcounts + pcsize;                   // 128
    int*   csr     = bsums + 128;                        // E
    float* pool16  = (float*)(csr + E);                  // N*16

    const int gTile = (N + 63) / 64;                     // 1563
    const int gRows = (N + 15) / 16;                     // 6250
    const int nCnt  = 256;
    const int nZero = 256;
    const int chunk = (E + B1 - 1) / B1;                 // 6250
    const int nS1   = (pcsize + 1023) >> 10;             // 98
    const int gAgg  = ((N + 15) / 16 + 3) / 4;           // 1563 (4 waves/block)

    // CSR build: LDS counting sort (no global atomics); p3 also zeroes cnt
    k_p1<<<B1, THREADS, 0, stream>>>(dst, pcounts, E, NB, chunk);
    k_s1<<<nS1, 1024, 0, stream>>>(pcounts, bsums, pcsize);
    k_s2<<<1, 128, 0, stream>>>(bsums, nS1);
    k_p2<<<B1, THREADS, 0, stream>>>(src, dst, pcounts, bsums, part, E, NB, chunk);
    k_p3<<<NB, THREADS, 0, stream>>>(part, pcounts, bsums, off, dinv, csr, cnt,
                                     E, NB, N);

    // GEMM1 (MFMA): bufA = bf16((x@W1)*dinv)  (+ cnt histogram + pool16 zero)
    k_mgemm<4, true><<<gTile + nCnt + nZero, THREADS, 0, stream>>>(
        x, nullptr, W1, dinv, bufA, N, dict, cnt, pool16, gTile, nCnt, nZero);

    // layer 1 MFMA aggregation + FUSED GEMM2: bufB = bf16((h1@W2)*dinv)
    k_agg<1><<<gAgg, THREADS, 0, stream>>>(bufA, csr, off, dinv, b1, bufB,
                                           W2, nullptr, nullptr, N);

    // layer 2 aggregation: gather bufB -> relu -> FC -> pool16
    k_agg<2><<<gAgg, THREADS, 0, stream>>>(bufB, csr, off, dinv, b2, nullptr,
                                           Wfc, dict, pool16, N);

    // mean + bias + log_softmax
    k_final16<<<gRows, THREADS, 0, stream>>>(pool16, cnt, bfc, (float*)d_out, N);
}